// Round 10
// baseline (97.854 us; speedup 1.0000x reference)
//
#include <hip/hip_runtime.h>

// Problem constants
#define Bn     8
#define Cn     64
#define Hn     96
#define Wn     96
#define HW     9216        // Hn*Wn
#define K2     9
#define COUTn  64
#define KDIM   576         // Cn*K2
#define NT     256
#define RECS   64          // f16 per HWC pixel record (128 B)
#define XH_HALFS ((size_t)Bn*HW*RECS)
#define XH_BYTES (XH_HALFS*2)              // 9,437,184
// Tile geometry: 16 wide x 4 tall = 64 pixels/block
#define TW     16
#define TH     4
#define TILES_X 6
#define BLKS_PER_IMG 144   // (96/16)*(96/4)
#define BLK_PIX 64
// LDS window: 24 cols x 11 rows of 128B f16 records, slot-swizzled (no pad)
#define WW     24
#define WH     11
#define WSTR   128                 // bytes per record in LDS (swizzle, no pad)
#define WDY    (WW*WSTR)           // 3072 = +1 row step
#define WIN_BYTES (WW*WH*WSTR)     // 33792
#define WCHUNK (WW*WH*8)           // 2112 16B chunks

typedef __attribute__((ext_vector_type(8))) _Float16 half8;    // 16 B = 4 VGPR
typedef __attribute__((ext_vector_type(4))) _Float16 half4v;   // 8 B
typedef __attribute__((ext_vector_type(4))) float    float4v;  // MFMA acc

// ---- Fused pre-pass: x NCHW f32 -> HWC f16 (slot-rotated) global; weight frag-major ----
// xh record for pixel p: slot s (16B, 8 ch) holds channel-group (s - p) & 7.
// wfrag layout: [mt(4)][kk(9)][ch(2)][lane(64)][j(8)]: A-fragment wave-load is
// 1024B contiguous. element: m=lane&15, q=lane>>4; cout=mt*16+m; c=ch*32+q*8+j.
__global__ __launch_bounds__(NT)
void prep_all(const float* __restrict__ x, _Float16* __restrict__ xh,
              const float* __restrict__ w, _Float16* __restrict__ wfrag) {
    const int blk = blockIdx.x;
    if (blk >= Bn * BLKS_PER_IMG) {
        int i = (blk - Bn * BLKS_PER_IMG) * NT + threadIdx.x;
        if (i < COUTn * KDIM) {
            int j    = i & 7;
            int lane = (i >> 3) & 63;
            int ch   = (i >> 9) & 1;
            int mk   = i >> 10;          // mt*9 + kk
            int kk   = mk % 9;
            int mt   = mk / 9;
            int m = lane & 15, q = lane >> 4;
            int cout = mt * 16 + m;
            int c    = ch * 32 + q * 8 + j;
            wfrag[i] = (_Float16)w[cout * KDIM + c * K2 + kk];
        }
        return;
    }
    __shared__ float tile[Cn * 65];     // 16.6 KB
    const int t    = threadIdx.x;
    const int lane = t & 63, wv = t >> 6;
    const int b    = blk & 7;
    const int pix0 = (blk >> 3) * BLK_PIX;   // linear 64-pixel groups

    #pragma unroll
    for (int i = 0; i < 16; ++i) {
        int c = wv + i * 4;
        tile[c * 65 + lane] = x[((size_t)b * Cn + c) * HW + pix0 + lane];
    }
    __syncthreads();
    #pragma unroll
    for (int pass = 0; pass < 4; ++pass) {
        int px  = wv * 16 + pass * 4 + (lane >> 4);
        int pix = pix0 + px;
        int c4  = (lane & 15) * 4;
        int g   = c4 >> 3;                       // channel group 0..7
        int slot = (g + pix) & 7;                // rotation by pixel
        half4v v;
        v[0] = (_Float16)tile[(c4 + 0) * 65 + px];
        v[1] = (_Float16)tile[(c4 + 1) * 65 + px];
        v[2] = (_Float16)tile[(c4 + 2) * 65 + px];
        v[3] = (_Float16)tile[(c4 + 3) * 65 + px];
        *(half4v*)&xh[((size_t)b * HW + pix) * RECS + slot * 8 + (c4 & 7)] = v;
    }
}

// ---- Main kernel: swizzled window staging, packed-f16 bilinear, f16 MFMA ----
__global__ __launch_bounds__(NT, 4)
void deform_conv_win(const float* __restrict__ x,          // NCHW f32 (fallback only)
                     const _Float16* __restrict__ xh,      // HWC f16, slot-rotated
                     const float* __restrict__ offset,
                     const _Float16* __restrict__ wfrag,
                     float* __restrict__ out) {
    __shared__ __align__(16) char smem[WIN_BYTES];  // 33 KB window; epilogue sC aliases
    __shared__ int    sA [K2 * BLK_PIX];   // 2.25 KB: rec*128 | u | dx | dy | ok
    __shared__ half4v sWh[K2 * BLK_PIX];   // 4.5 KB bilinear weights (f16)

    const int tid  = threadIdx.x;
    const int b    = blockIdx.x & 7;                 // XCD swizzle
    const int tl   = blockIdx.x >> 3;
    const int ty0  = (tl / TILES_X) * TH;
    const int tx0  = (tl % TILES_X) * TW;
    const int wy0  = min(max(ty0 - 3, 0), Hn - WH);  // window origin (in-image)
    const int wx0  = min(max(tx0 - 4, 0), Wn - WW);

    const float* xb   = x + (size_t)b * (Cn * HW);
    const float* offb = offset + (size_t)b * (2 * K2 * HW);

    const int lane = tid & 63;
    const int wv   = tid >> 6;

    // ---- Phase 0a: sampling metadata per (kk, pixel) ----
    for (int e = tid; e < K2 * BLK_PIX; e += NT) {
        int kk = e >> 6;
        int pl = e & 63;
        int h = ty0 + (pl >> 4);
        int w = tx0 + (pl & 15);
        int pix = h * 96 + w;
        float offy = offb[(2 * kk) * HW + pix];
        float offx = offb[(2 * kk + 1) * HW + pix];
        float py = (float)(h - 1 + kk / 3) + offy;
        float px = (float)(w - 1 + kk % 3) + offx;
        float y0f = floorf(py), x0f = floorf(px);
        float ly = py - y0f, lx = px - x0f;
        int y0 = (int)y0f, x0 = (int)x0f;
        float vy0 = ((unsigned)y0 < 96u) ? 1.f : 0.f;
        float vy1 = ((unsigned)(y0 + 1) < 96u) ? 1.f : 0.f;
        float vx0 = ((unsigned)x0 < 96u) ? 1.f : 0.f;
        float vx1 = ((unsigned)(x0 + 1) < 96u) ? 1.f : 0.f;
        float w00 = (1.f - ly) * (1.f - lx) * vy0 * vx0;
        float w01 = (1.f - ly) * lx         * vy0 * vx1;
        float w10 = ly * (1.f - lx)         * vy1 * vx0;
        float w11 = ly * lx                 * vy1 * vx1;
        int y0c = min(max(y0, 0), 95);
        int x0c = min(max(x0, 0), 95);
        int dx = min(max(x0 + 1, 0), 95) - x0c;   // 0 or 1
        int dy = min(max(y0 + 1, 0), 95) - y0c;   // 0 or 1
        int ok = (y0c >= wy0) & (y0c + dy <= wy0 + WH - 1) &
                 (x0c >= wx0) & (x0c + dx <= wx0 + WW - 1);
        int rec = (y0c - wy0) * WW + (x0c - wx0);
        int u   = (rec + wx0) & 7;                // slot rotation base
        sA [e] = ok ? ((rec * WSTR) | (u << 16) | (dx << 19) | (dy << 20) | (1 << 21)) : 0;
        half4v hv;
        hv[0] = (_Float16)w00; hv[1] = (_Float16)w01;
        hv[2] = (_Float16)w10; hv[3] = (_Float16)w11;
        sWh[e] = hv;
    }

    // ---- Phase 0b: stage 24x11 window (dense 16B chunks, LDS dest = c*16) ----
    {
        const _Float16* src = xh + ((size_t)b * HW + wy0 * 96 + wx0) * RECS;
        #pragma unroll
        for (int i = 0; i < 9; ++i) {
            int c = i * NT + tid;            // 0..2303, valid < 2112
            if (c < WCHUNK) {
                int rec = c >> 3;
                int s   = c & 7;
                int row = rec / WW;
                int col = rec - row * WW;
                const _Float16* g = src + ((size_t)row * 96 + col) * RECS + s * 8;
                *(half8*)(smem + c * 16) = *(const half8*)g;
            }
        }
    }
    __syncthreads();

    const int q    = lane >> 4;          // quad 0..3
    const int r    = lane & 15;          // 0..15
    const int plw  = wv * 16 + r;        // B-column pixel (local)

    float4v acc0 = {0.f,0.f,0.f,0.f};
    float4v acc1 = {0.f,0.f,0.f,0.f};
    float4v acc2 = {0.f,0.f,0.f,0.f};
    float4v acc3 = {0.f,0.f,0.f,0.f};

    const _Float16* wlane = wfrag + lane * 8;

    for (int kk = 0; kk < 9; ++kk) {
        const int idx = kk * BLK_PIX + plw;
        const int pk  = sA[idx];
        const half4v hv = sWh[idx];
        const _Float16 w0 = hv[0], w1 = hv[1], w2 = hv[2], w3 = hv[3];

        half8 bq0, bq1;
        if (pk & (1 << 21)) {
            // LDS window path (taken except ~1e-4 of samples); swizzled slots
            const int A   = pk & 0xFFFF;              // rec*128
            const int u   = (pk >> 16) & 7;
            const int dxv = (pk >> 19) & 1;
            const int dyv = (pk >> 20) & 1;
            const int s0  = (u + q) & 7;              // slot for group q
            const int s0d = (s0 + dxv) & 7;           // +dx rotates by 1
            const int A01 = A + dxv * WSTR;
            const int A10 = A + dyv * WDY;            // +row: slot unchanged (24%8==0)
            const int A11 = A10 + dxv * WSTR;
            half8 s00a = *(const half8*)(smem + A   + s0  * 16);
            half8 s01a = *(const half8*)(smem + A01 + s0d * 16);
            half8 s10a = *(const half8*)(smem + A10 + s0  * 16);
            half8 s11a = *(const half8*)(smem + A11 + s0d * 16);
            half8 s00b = *(const half8*)(smem + A   + (s0  ^ 4) * 16);
            half8 s01b = *(const half8*)(smem + A01 + (s0d ^ 4) * 16);
            half8 s10b = *(const half8*)(smem + A10 + (s0  ^ 4) * 16);
            half8 s11b = *(const half8*)(smem + A11 + (s0d ^ 4) * 16);
            bq0 = s00a * w0 + s01a * w1 + s10a * w2 + s11a * w3;
            bq1 = s00b * w0 + s01b * w1 + s10b * w2 + s11b * w3;
        } else {
            // Global f32 fallback (pathological offsets only): recompute coords
            const int h = ty0 + (plw >> 4), w = tx0 + (plw & 15);
            const int pix = h * 96 + w;
            const float offy = offb[(2 * kk) * HW + pix];
            const float offx = offb[(2 * kk + 1) * HW + pix];
            const float py = (float)(h - 1 + kk / 3) + offy;
            const float px = (float)(w - 1 + kk % 3) + offx;
            const int y0 = (int)floorf(py), x0 = (int)floorf(px);
            const int y0c = min(max(y0, 0), 95);
            const int x0c = min(max(x0, 0), 95);
            const int dxv = min(max(x0 + 1, 0), 95) - x0c;
            const int dyr = (min(max(y0 + 1, 0), 95) - y0c) * 96;
            const int a00p = y0c * 96 + x0c;
            const float f0 = (float)w0, f1 = (float)w1, f2 = (float)w2, f3 = (float)w3;
            #pragma unroll
            for (int ch = 0; ch < 2; ++ch) {
                #pragma unroll
                for (int j = 0; j < 8; ++j) {
                    int c = ch * 32 + q * 8 + j;
                    const float* xc = xb + (size_t)c * HW + a00p;
                    float v = fmaf(f0, xc[0],
                              fmaf(f1, xc[dxv],
                              fmaf(f2, xc[dyr],
                                   f3 * xc[dyr + dxv])));
                    if (ch) bq1[j] = (_Float16)v; else bq0[j] = (_Float16)v;
                }
            }
        }

        // A fragments: dense 1024B wave-loads from fragment-major wfrag
        const _Float16* wkc = wlane + (size_t)kk * 1024;     // [mt][kk][ch]...
        half8 a00 = *(const half8*)(wkc + 0 * 9216);
        half8 a10 = *(const half8*)(wkc + 1 * 9216);
        half8 a20 = *(const half8*)(wkc + 2 * 9216);
        half8 a30 = *(const half8*)(wkc + 3 * 9216);
        acc0 = __builtin_amdgcn_mfma_f32_16x16x32_f16(a00, bq0, acc0, 0, 0, 0);
        acc1 = __builtin_amdgcn_mfma_f32_16x16x32_f16(a10, bq0, acc1, 0, 0, 0);
        acc2 = __builtin_amdgcn_mfma_f32_16x16x32_f16(a20, bq0, acc2, 0, 0, 0);
        acc3 = __builtin_amdgcn_mfma_f32_16x16x32_f16(a30, bq0, acc3, 0, 0, 0);
        half8 a01 = *(const half8*)(wkc + 512 + 0 * 9216);
        half8 a11 = *(const half8*)(wkc + 512 + 1 * 9216);
        half8 a21 = *(const half8*)(wkc + 512 + 2 * 9216);
        half8 a31 = *(const half8*)(wkc + 512 + 3 * 9216);
        acc0 = __builtin_amdgcn_mfma_f32_16x16x32_f16(a01, bq1, acc0, 0, 0, 0);
        acc1 = __builtin_amdgcn_mfma_f32_16x16x32_f16(a11, bq1, acc1, 0, 0, 0);
        acc2 = __builtin_amdgcn_mfma_f32_16x16x32_f16(a21, bq1, acc2, 0, 0, 0);
        acc3 = __builtin_amdgcn_mfma_f32_16x16x32_f16(a31, bq1, acc3, 0, 0, 0);
    }

    // ---- Epilogue: stage through LDS (aliases window) for dense stores ----
    __syncthreads();                       // all window reads done; reuse smem
    float* sC = (float*)smem;              // [64][68] floats = 17.4 KB <= 33 KB
    #pragma unroll
    for (int mt = 0; mt < 4; ++mt) {
        float4v a = (mt == 0) ? acc0 : (mt == 1) ? acc1 : (mt == 2) ? acc2 : acc3;
        int cout = mt * 16 + q * 4;
        #pragma unroll
        for (int reg = 0; reg < 4; ++reg)
            sC[(cout + reg) * 68 + plw] = a[reg];
    }
    __syncthreads();

    #pragma unroll
    for (int i = 0; i < 4; ++i) {
        int idx  = i * NT + tid;
        int cout = idx >> 4;
        int px4  = (idx & 15) * 4;         // local pixel 0..60
        int row  = px4 >> 4;
        int col  = px4 & 15;
        float4 v = *(const float4*)&sC[cout * 68 + px4];
        *(float4*)&out[((size_t)(b * COUTn + cout)) * HW + (ty0 + row) * 96 + tx0 + col] = v;
    }
}

extern "C" void kernel_launch(void* const* d_in, const int* in_sizes, int n_in,
                              void* d_out, int out_size, void* d_ws, size_t ws_size,
                              hipStream_t stream) {
    const float* x      = (const float*)d_in[0];
    const float* offset = (const float*)d_in[1];
    const float* weight = (const float*)d_in[2];
    float* out = (float*)d_out;

    _Float16* xh    = (_Float16*)d_ws;                          // 9,437,184 B
    _Float16* wfrag = (_Float16*)((char*)d_ws + XH_BYTES);      // 73,728 B

    prep_all<<<dim3(Bn * BLKS_PER_IMG + 144), dim3(NT), 0, stream>>>(x, xh, weight, wfrag);
    deform_conv_win<<<dim3(Bn * BLKS_PER_IMG), dim3(NT), 0, stream>>>(x, xh, offset, wfrag, out);
}

// Round 11
// 95.650 us; speedup vs baseline: 1.0230x; 1.0230x over previous
//
#include <hip/hip_runtime.h>

// Problem constants
#define Bn     8
#define Cn     64
#define Hn     96
#define Wn     96
#define HW     9216        // Hn*Wn
#define K2     9
#define COUTn  64
#define KDIM   576         // Cn*K2
#define NT     256
#define RECS   64          // f16 per HWC pixel record (128 B)
#define XH_HALFS ((size_t)Bn*HW*RECS)
#define XH_BYTES (XH_HALFS*2)              // 9,437,184
// Tile geometry: 16 wide x 4 tall = 64 pixels/block
#define TW     16
#define TH     4
#define TILES_X 6
#define BLKS_PER_IMG 144   // (96/16)*(96/4)
#define BLK_PIX 64
// LDS window: 24 cols x 12 rows of 128B f16 records, padded to 144B stride
#define WW     24
#define WH     12
#define WSTR   144                 // bytes per record in LDS (pad 16)
#define WDY    (WW*WSTR)           // 3456 = +1 row step
#define WIN_BYTES (WW*WH*WSTR)     // 41472
#define WCHUNKS (WW*WH*8)          // 2304 16B chunks = 9 per thread

typedef __attribute__((ext_vector_type(8))) _Float16 half8;    // 16 B = 4 VGPR
typedef __attribute__((ext_vector_type(4))) _Float16 half4v;   // 8 B
typedef __attribute__((ext_vector_type(4))) float    float4v;  // MFMA acc

// ---- Fused pre-pass: x NCHW f32 -> HWC f16 global; weight -> f16 frag-major ----
// wfrag layout: [mt(4)][kk(9)][ch(2)][lane(64)][j(8)]: A-fragment wave-load is
// 1024B contiguous. element: m=lane&15, q=lane>>4; cout=mt*16+m; c=ch*32+q*8+j.
__global__ __launch_bounds__(NT)
void prep_all(const float* __restrict__ x, _Float16* __restrict__ xh,
              const float* __restrict__ w, _Float16* __restrict__ wfrag) {
    const int blk = blockIdx.x;
    if (blk >= Bn * BLKS_PER_IMG) {
        int i = (blk - Bn * BLKS_PER_IMG) * NT + threadIdx.x;
        if (i < COUTn * KDIM) {
            int j    = i & 7;
            int lane = (i >> 3) & 63;
            int ch   = (i >> 9) & 1;
            int mk   = i >> 10;          // mt*9 + kk
            int kk   = mk % 9;
            int mt   = mk / 9;
            int m = lane & 15, q = lane >> 4;
            int cout = mt * 16 + m;
            int c    = ch * 32 + q * 8 + j;
            wfrag[i] = (_Float16)w[cout * KDIM + c * K2 + kk];
        }
        return;
    }
    __shared__ float tile[Cn * 65];     // 16.6 KB
    const int t    = threadIdx.x;
    const int lane = t & 63, wv = t >> 6;
    const int b    = blk & 7;
    const int pix0 = (blk >> 3) * BLK_PIX;   // linear 64-pixel groups

    #pragma unroll
    for (int i = 0; i < 16; ++i) {
        int c = wv + i * 4;
        tile[c * 65 + lane] = x[((size_t)b * Cn + c) * HW + pix0 + lane];
    }
    __syncthreads();
    #pragma unroll
    for (int pass = 0; pass < 4; ++pass) {
        int px = wv * 16 + pass * 4 + (lane >> 4);
        int c4 = (lane & 15) * 4;
        half4v v;
        v[0] = (_Float16)tile[(c4 + 0) * 65 + px];
        v[1] = (_Float16)tile[(c4 + 1) * 65 + px];
        v[2] = (_Float16)tile[(c4 + 2) * 65 + px];
        v[3] = (_Float16)tile[(c4 + 3) * 65 + px];
        *(half4v*)&xh[((size_t)b * HW + pix0 + px) * RECS + c4] = v;
    }
}

// ---- Main kernel: dense HWC-f16 window staging, packed-f16 bilinear, f16 MFMA ----
__global__ __launch_bounds__(NT, 3)
void deform_conv_win(const float* __restrict__ x,          // NCHW f32 (fallback only)
                     const _Float16* __restrict__ xh,      // HWC f16
                     const float* __restrict__ offset,
                     const _Float16* __restrict__ wfrag,
                     float* __restrict__ out) {
    __shared__ __align__(16) char smem[WIN_BYTES];  // 41.5 KB window; epilogue sC aliases
    __shared__ int    sA [K2 * BLK_PIX];   // 2.25 KB: LDS off | dx | dy | ok
    __shared__ int    sA2[K2 * BLK_PIX];   // 2.25 KB: global pack (fallback)
    __shared__ half4v sWh[K2 * BLK_PIX];   // 4.5 KB bilinear weights (f16)

    const int tid  = threadIdx.x;
    const int b    = blockIdx.x & 7;                 // XCD swizzle
    const int tl   = blockIdx.x >> 3;
    const int ty0  = (tl / TILES_X) * TH;
    const int tx0  = (tl % TILES_X) * TW;
    const int wy0  = min(max(ty0 - 4, 0), Hn - WH);  // window origin (in-image)
    const int wx0  = min(max(tx0 - 4, 0), Wn - WW);

    const float* xb   = x + (size_t)b * (Cn * HW);
    const float* offb = offset + (size_t)b * (2 * K2 * HW);

    const int lane = tid & 63;
    const int wv   = tid >> 6;

    // ---- Phase 0a: sampling metadata per (kk, pixel) ----
    for (int e = tid; e < K2 * BLK_PIX; e += NT) {
        int kk = e >> 6;
        int pl = e & 63;
        int h = ty0 + (pl >> 4);
        int w = tx0 + (pl & 15);
        int pix = h * 96 + w;
        float offy = offb[(2 * kk) * HW + pix];
        float offx = offb[(2 * kk + 1) * HW + pix];
        float py = (float)(h - 1 + kk / 3) + offy;
        float px = (float)(w - 1 + kk % 3) + offx;
        float y0f = floorf(py), x0f = floorf(px);
        float ly = py - y0f, lx = px - x0f;
        int y0 = (int)y0f, x0 = (int)x0f;
        float vy0 = ((unsigned)y0 < 96u) ? 1.f : 0.f;
        float vy1 = ((unsigned)(y0 + 1) < 96u) ? 1.f : 0.f;
        float vx0 = ((unsigned)x0 < 96u) ? 1.f : 0.f;
        float vx1 = ((unsigned)(x0 + 1) < 96u) ? 1.f : 0.f;
        float w00 = (1.f - ly) * (1.f - lx) * vy0 * vx0;
        float w01 = (1.f - ly) * lx         * vy0 * vx1;
        float w10 = ly * (1.f - lx)         * vy1 * vx0;
        float w11 = ly * lx                 * vy1 * vx1;
        int y0c = min(max(y0, 0), 95);
        int x0c = min(max(x0, 0), 95);
        int dx = min(max(x0 + 1, 0), 95) - x0c;   // 0 or 1
        int dy = min(max(y0 + 1, 0), 95) - y0c;   // 0 or 1
        int ok = (y0c >= wy0) & (y0c + dy <= wy0 + WH - 1) &
                 (x0c >= wx0) & (x0c + dx <= wx0 + WW - 1);
        int woff = ok ? ((y0c - wy0) * WW + (x0c - wx0)) * WSTR : 0;
        sA [e] = woff | (dx << 16) | (dy << 17) | (ok << 18);
        sA2[e] = (y0c * 96 + x0c) | (dx << 14) | (dy << 15);
        half4v hv;
        hv[0] = (_Float16)w00; hv[1] = (_Float16)w01;
        hv[2] = (_Float16)w10; hv[3] = (_Float16)w11;
        sWh[e] = hv;
    }

    // ---- Phase 0b: stage 24x12 window from HWC f16 (dense, 16 lines/wave-instr) ----
    {
        const _Float16* src = xh + ((size_t)b * HW + wy0 * 96 + wx0) * RECS;
        #pragma unroll
        for (int i = 0; i < 9; ++i) {
            int c   = i * NT + tid;         // 0..2303
            int rec = c >> 3;
            int w16 = c & 7;
            int row = rec / WW;
            int col = rec - row * WW;
            const _Float16* g = src + ((size_t)row * 96 + col) * RECS + w16 * 8;
            *(half8*)(smem + rec * WSTR + w16 * 16) = *(const half8*)g;
        }
    }
    __syncthreads();

    const int q    = lane >> 4;          // quad 0..3
    const int r    = lane & 15;          // 0..15
    const int plw  = wv * 16 + r;        // B-column pixel (local)

    float4v acc0 = {0.f,0.f,0.f,0.f};
    float4v acc1 = {0.f,0.f,0.f,0.f};
    float4v acc2 = {0.f,0.f,0.f,0.f};
    float4v acc3 = {0.f,0.f,0.f,0.f};

    const _Float16* wlane = wfrag + lane * 8;

    for (int kk = 0; kk < 9; ++kk) {
        const int idx = kk * BLK_PIX + plw;
        const int pk  = sA[idx];
        const half4v hv = sWh[idx];
        const _Float16 w0 = hv[0], w1 = hv[1], w2 = hv[2], w3 = hv[3];

        half8 bq0, bq1;
        if (pk & (1 << 18)) {
            // LDS window path (always taken for this data); packed v_pk_fma_f16
            const char* base = smem + (pk & 0xFFFF) + q * 16;
            const int dxs = ((pk >> 16) & 1) * WSTR;
            const int dys = ((pk >> 17) & 1) * WDY;
            half8 s00a = *(const half8*)(base);
            half8 s01a = *(const half8*)(base + dxs);
            half8 s10a = *(const half8*)(base + dys);
            half8 s11a = *(const half8*)(base + dys + dxs);
            half8 s00b = *(const half8*)(base + 64);
            half8 s01b = *(const half8*)(base + 64 + dxs);
            half8 s10b = *(const half8*)(base + 64 + dys);
            half8 s11b = *(const half8*)(base + 64 + dys + dxs);
            bq0 = s00a * w0 + s01a * w1 + s10a * w2 + s11a * w3;
            bq1 = s00b * w0 + s01b * w1 + s10b * w2 + s11b * w3;
        } else {
            // Global f32 fallback (pathological offsets only; correct, slow)
            const int pk2  = sA2[idx];
            const int a00p = pk2 & 16383;
            const int dxv  = (pk2 >> 14) & 1;
            const int dyr  = ((pk2 >> 15) & 1) * 96;
            const float f0 = (float)w0, f1 = (float)w1, f2 = (float)w2, f3 = (float)w3;
            #pragma unroll
            for (int ch = 0; ch < 2; ++ch) {
                #pragma unroll
                for (int j = 0; j < 8; ++j) {
                    int c = ch * 32 + q * 8 + j;
                    const float* xc = xb + (size_t)c * HW + a00p;
                    float v = fmaf(f0, xc[0],
                              fmaf(f1, xc[dxv],
                              fmaf(f2, xc[dyr],
                                   f3 * xc[dyr + dxv])));
                    if (ch) bq1[j] = (_Float16)v; else bq0[j] = (_Float16)v;
                }
            }
        }

        // A fragments: dense 1024B wave-loads from fragment-major wfrag
        const _Float16* wkc = wlane + (size_t)kk * 1024;     // [mt][kk][ch]...
        half8 a00 = *(const half8*)(wkc + 0 * 9216);
        half8 a10 = *(const half8*)(wkc + 1 * 9216);
        half8 a20 = *(const half8*)(wkc + 2 * 9216);
        half8 a30 = *(const half8*)(wkc + 3 * 9216);
        acc0 = __builtin_amdgcn_mfma_f32_16x16x32_f16(a00, bq0, acc0, 0, 0, 0);
        acc1 = __builtin_amdgcn_mfma_f32_16x16x32_f16(a10, bq0, acc1, 0, 0, 0);
        acc2 = __builtin_amdgcn_mfma_f32_16x16x32_f16(a20, bq0, acc2, 0, 0, 0);
        acc3 = __builtin_amdgcn_mfma_f32_16x16x32_f16(a30, bq0, acc3, 0, 0, 0);
        half8 a01 = *(const half8*)(wkc + 512 + 0 * 9216);
        half8 a11 = *(const half8*)(wkc + 512 + 1 * 9216);
        half8 a21 = *(const half8*)(wkc + 512 + 2 * 9216);
        half8 a31 = *(const half8*)(wkc + 512 + 3 * 9216);
        acc0 = __builtin_amdgcn_mfma_f32_16x16x32_f16(a01, bq1, acc0, 0, 0, 0);
        acc1 = __builtin_amdgcn_mfma_f32_16x16x32_f16(a11, bq1, acc1, 0, 0, 0);
        acc2 = __builtin_amdgcn_mfma_f32_16x16x32_f16(a21, bq1, acc2, 0, 0, 0);
        acc3 = __builtin_amdgcn_mfma_f32_16x16x32_f16(a31, bq1, acc3, 0, 0, 0);
    }

    // ---- Epilogue: stage through LDS (aliases window) for dense stores ----
    __syncthreads();                       // all window reads done; reuse smem
    float* sC = (float*)smem;              // [64][68] floats = 17.4 KB
    #pragma unroll
    for (int mt = 0; mt < 4; ++mt) {
        float4v a = (mt == 0) ? acc0 : (mt == 1) ? acc1 : (mt == 2) ? acc2 : acc3;
        int cout = mt * 16 + q * 4;
        #pragma unroll
        for (int reg = 0; reg < 4; ++reg)
            sC[(cout + reg) * 68 + plw] = a[reg];
    }
    __syncthreads();

    #pragma unroll
    for (int i = 0; i < 4; ++i) {
        int idx  = i * NT + tid;
        int cout = idx >> 4;
        int px4  = (idx & 15) * 4;         // local pixel 0..60
        int row  = px4 >> 4;
        int col  = px4 & 15;
        float4 v = *(const float4*)&sC[cout * 68 + px4];
        *(float4*)&out[((size_t)(b * COUTn + cout)) * HW + (ty0 + row) * 96 + tx0 + col] = v;
    }
}

extern "C" void kernel_launch(void* const* d_in, const int* in_sizes, int n_in,
                              void* d_out, int out_size, void* d_ws, size_t ws_size,
                              hipStream_t stream) {
    const float* x      = (const float*)d_in[0];
    const float* offset = (const float*)d_in[1];
    const float* weight = (const float*)d_in[2];
    float* out = (float*)d_out;

    _Float16* xh    = (_Float16*)d_ws;                          // 9,437,184 B
    _Float16* wfrag = (_Float16*)((char*)d_ws + XH_BYTES);      // 73,728 B

    prep_all<<<dim3(Bn * BLKS_PER_IMG + 144), dim3(NT), 0, stream>>>(x, xh, weight, wfrag);
    deform_conv_win<<<dim3(Bn * BLKS_PER_IMG), dim3(NT), 0, stream>>>(x, xh, offset, wfrag, out);
}